// Round 9
// baseline (241.889 us; speedup 1.0000x reference)
//
#include <hip/hip_runtime.h>
#include <hip/hip_fp16.h>
#include <hip/hip_cooperative_groups.h>

namespace cg = cooperative_groups;

#define GYD 512
#define GXD 512
#define HD 256
#define WD 256
#define BD 8
#define NSAMP 100000
#define JD 7
#define NCHUNK 3125      // 32-sample gather chunks
#define NBLK 512

// digit-reverse base 8, 3 digits (involution)
__device__ __forceinline__ int dr3(int i) {
    return ((i & 7) << 6) | (i & 56) | ((i >> 6) & 7);
}

// One radix-8 DIT stage over (1<<CLOG) interleaved 512-pt FFTs in LDS.
// Column stride = (1<<CLOG)+1 (pad). g = butterfly id: c = g & mask, m = g >> CLOG.
template<int LEN, int EIGHTH, int TWSH, int CLOG>
__device__ __forceinline__ void r8_stage(float* __restrict__ re, float* __restrict__ im,
                                         const float* __restrict__ twr,
                                         const float* __restrict__ twi, int g) {
    const int STR = (1 << CLOG) + 1;
    const int c = g & ((1 << CLOG) - 1);
    const int m = g >> CLOG;
    const int off = m & (EIGHTH - 1);
    const int blk = m / EIGHTH;
    const int p0 = (blk * LEN + off) * STR + c;
    float ar[8], ai[8];
    #pragma unroll
    for (int j = 0; j < 8; ++j) {
        ar[j] = re[p0 + j * EIGHTH * STR];
        ai[j] = im[p0 + j * EIGHTH * STR];
    }
    if (TWSH >= 0) {
        #pragma unroll
        for (int j = 1; j < 8; ++j) {
            const int idx = (off * j) << (TWSH >= 0 ? TWSH : 0);
            const float cr = twr[idx], ci = twi[idx];
            const float tr = ar[j] * cr - ai[j] * ci;
            ai[j] = ar[j] * ci + ai[j] * cr;
            ar[j] = tr;
        }
    }
    const float e0r = ar[0] + ar[4], e0i = ai[0] + ai[4];
    const float e1r = ar[0] - ar[4], e1i = ai[0] - ai[4];
    const float e2r = ar[2] + ar[6], e2i = ai[2] + ai[6];
    const float e3r = ar[2] - ar[6], e3i = ai[2] - ai[6];
    const float E0r = e0r + e2r, E0i = e0i + e2i;
    const float E2r = e0r - e2r, E2i = e0i - e2i;
    const float E1r = e1r + e3i, E1i = e1i - e3r;   // e1 - i*e3
    const float E3r = e1r - e3i, E3i = e1i + e3r;   // e1 + i*e3

    const float q0r = ar[1] + ar[5], q0i = ai[1] + ai[5];
    const float q1r = ar[1] - ar[5], q1i = ai[1] - ai[5];
    const float q2r = ar[3] + ar[7], q2i = ai[3] + ai[7];
    const float q3r = ar[3] - ar[7], q3i = ai[3] - ai[7];
    const float O0r = q0r + q2r, O0i = q0i + q2i;
    const float O2r = q0r - q2r, O2i = q0i - q2i;
    const float O1r = q1r + q3i, O1i = q1i - q3r;
    const float O3r = q1r - q3i, O3i = q1i + q3r;

    const float S = 0.70710678118654752f;
    const float T0r = O0r,              T0i = O0i;
    const float T1r = S * (O1r + O1i),  T1i = S * (O1i - O1r);
    const float T2r = O2i,              T2i = -O2r;
    const float T3r = S * (O3i - O3r),  T3i = -S * (O3r + O3i);

    re[p0 + 0 * EIGHTH * STR] = E0r + T0r;  im[p0 + 0 * EIGHTH * STR] = E0i + T0i;
    re[p0 + 4 * EIGHTH * STR] = E0r - T0r;  im[p0 + 4 * EIGHTH * STR] = E0i - T0i;
    re[p0 + 1 * EIGHTH * STR] = E1r + T1r;  im[p0 + 1 * EIGHTH * STR] = E1i + T1i;
    re[p0 + 5 * EIGHTH * STR] = E1r - T1r;  im[p0 + 5 * EIGHTH * STR] = E1i - T1i;
    re[p0 + 2 * EIGHTH * STR] = E2r + T2r;  im[p0 + 2 * EIGHTH * STR] = E2i + T2i;
    re[p0 + 6 * EIGHTH * STR] = E2r - T2r;  im[p0 + 6 * EIGHTH * STR] = E2i - T2i;
    re[p0 + 3 * EIGHTH * STR] = E3r + T3r;  im[p0 + 3 * EIGHTH * STR] = E3i + T3i;
    re[p0 + 7 * EIGHTH * STR] = E3r - T3r;  im[p0 + 7 * EIGHTH * STR] = E3i - T3i;
}

// Fused pipeline: rowFFT -> grid.sync -> colFFT(fp16 out) -> grid.sync -> gather.
// 512 blocks x 256 threads, 2 blocks/CU co-resident (cooperative launch).
__global__ __launch_bounds__(256, 2) void fused_kernel(
    const float* __restrict__ xr, const float* __restrict__ xi,
    const float* __restrict__ sc_y, const float* __restrict__ sc_x,
    const float* __restrict__ wy, const float* __restrict__ wx,
    const float* __restrict__ phr, const float* __restrict__ phi,
    const int* __restrict__ iy, const int* __restrict__ ix,
    float4* __restrict__ G1i4, float2* __restrict__ ghat_f2,
    float2* __restrict__ out)
{
    __shared__ float re[512 * 9];
    __shared__ float im[512 * 9];
    __shared__ float twr[512];
    __shared__ float twi[512];
    __shared__ int   s_iy[32 * JD];
    __shared__ int   s_ix[32 * JD];
    __shared__ float s_wy[32 * JD];
    __shared__ float s_wx[32 * JD];
    __shared__ float s_pr[32];
    __shared__ float s_pi[32];

    cg::grid_group grid = cg::this_grid();
    const int t = threadIdx.x;

    // twiddle table: tw[m] = exp(-2*pi*i*m/512)
    #pragma unroll
    for (int k = 0; k < 2; ++k) {
        const int m = k * 256 + t;
        float sn, cs;
        sincospif(-(float)m / 256.0f, &sn, &cs);
        twr[m] = cs; twi[m] = sn;
    }

    // ---------------- Phase A: row FFT (4 batches per block) ----------------
    {
        const int y = blockIdx.x >> 1;
        const int half = blockIdx.x & 1;
        const int bl = t >> 6;               // local batch 0..3
        const int b = half * 4 + bl;
        const int x4 = (t & 63) << 2;        // 0..252 step 4
        const float sy = sc_y[y];
        const float4 vr = *(const float4*)(xr + b * (HD * WD) + y * WD + x4);
        const float4 vi = *(const float4*)(xi + b * (HD * WD) + y * WD + x4);
        const float4 sx = *(const float4*)(sc_x + x4);
        int p; float s;
        s = sy * sx.x; p = dr3(x4 + 0) * 5 + bl; re[p] = vr.x * s; im[p] = vi.x * s;
        s = sy * sx.y; p = dr3(x4 + 1) * 5 + bl; re[p] = vr.y * s; im[p] = vi.y * s;
        s = sy * sx.z; p = dr3(x4 + 2) * 5 + bl; re[p] = vr.z * s; im[p] = vi.z * s;
        s = sy * sx.w; p = dr3(x4 + 3) * 5 + bl; re[p] = vr.w * s; im[p] = vi.w * s;
        #pragma unroll
        for (int k = 0; k < 4; ++k) {        // x zero-pad 256..511
            p = dr3(x4 + 256 + k) * 5 + bl;
            re[p] = 0.0f; im[p] = 0.0f;
        }
        __syncthreads();
        r8_stage<8, 1, -1, 2>(re, im, twr, twi, t);
        __syncthreads();
        r8_stage<64, 8, 3, 2>(re, im, twr, twi, t);
        __syncthreads();
        r8_stage<512, 64, 0, 2>(re, im, twr, twi, t);
        __syncthreads();

        // write interleaved G1i: float4 slot (y*512+x)*4 + half*2 + k
        float4* dst = G1i4 + (size_t)y * 2048;
        #pragma unroll
        for (int iter = 0; iter < 4; ++iter) {
            const int i = iter * 256 + t;    // 0..1023
            const int x = i >> 1;
            const int k = i & 1;
            const int p = x * 5 + k * 2;
            dst[(size_t)x * 4 + half * 2 + k] =
                make_float4(re[p], im[p], re[p + 1], im[p + 1]);
        }
    }
    grid.sync();

    // ---------------- Phase B: column FFT, fp16 out (one x per block) -------
    {
        const int x = blockIdx.x;
        #pragma unroll
        for (int iter = 0; iter < 4; ++iter) {
            const int i = iter * 256 + t;    // 0..1023
            const int yy = i >> 2;           // 0..255
            const int slot = i & 3;
            const int bp = slot << 1;
            const float4 v = G1i4[((size_t)yy * GXD + x) * 4 + slot];
            const int p = dr3(yy) * 9 + bp;
            re[p] = v.x; im[p] = v.y; re[p + 1] = v.z; im[p + 1] = v.w;
            const int p2 = dr3(yy + 256) * 9 + bp;   // y zero-pad
            re[p2] = 0.0f; im[p2] = 0.0f; re[p2 + 1] = 0.0f; im[p2 + 1] = 0.0f;
        }
        __syncthreads();
        r8_stage<8, 1, -1, 3>(re, im, twr, twi, t);
        r8_stage<8, 1, -1, 3>(re, im, twr, twi, t + 256);
        __syncthreads();
        r8_stage<64, 8, 3, 3>(re, im, twr, twi, t);
        r8_stage<64, 8, 3, 3>(re, im, twr, twi, t + 256);
        __syncthreads();
        r8_stage<512, 64, 0, 3>(re, im, twr, twi, t);
        r8_stage<512, 64, 0, 3>(re, im, twr, twi, t + 256);
        __syncthreads();

        const float scale = 1.0f / 512.0f;   // ortho: 1/sqrt(512*512)
        #pragma unroll
        for (int iter = 0; iter < 8; ++iter) {
            const int if4 = iter * 256 + t;  // 0..2047
            const int yy = if4 >> 2;         // 0..511
            const int b = (if4 & 3) << 1;
            const int p = yy * 9 + b;
            union { __half2 h[2]; float2 f; } u;
            u.h[0] = __floats2half2_rn(re[p] * scale,     im[p] * scale);
            u.h[1] = __floats2half2_rn(re[p + 1] * scale, im[p + 1] * scale);
            ghat_f2[((size_t)yy * GXD + x) * 4 + (b >> 1)] = u.f;
        }
    }
    grid.sync();

    // ---------------- Phase C: gather (grid-strided 32-sample chunks) -------
    const __half2* __restrict__ gh = (const __half2*)ghat_f2;
    for (int chunk = blockIdx.x; chunk < NCHUNK; chunk += NBLK) {
        const int n0 = chunk * 32;
        __syncthreads();
        if (t < 224) {                       // 32 samples x 7 taps, coalesced
            const int g = n0 * JD + t;
            s_iy[t] = iy[g];
            s_ix[t] = ix[g];
            s_wy[t] = wy[g];
            s_wx[t] = wx[g];
        } else {
            const int s = t - 224;
            s_pr[s] = phr[n0 + s];
            s_pi[s] = phi[n0 + s];
        }
        __syncthreads();

        const int b = t & 7;
        const int s = t >> 3;                // local sample 0..31
        const int base = s * JD;
        int iyl[JD], ixl[JD];
        float wyl[JD], wxl[JD];
        #pragma unroll
        for (int j = 0; j < JD; ++j) {
            iyl[j] = s_iy[base + j];
            ixl[j] = s_ix[base + j];
            wyl[j] = s_wy[base + j];
            wxl[j] = s_wx[base + j];
        }

        float ar = 0.0f, ai = 0.0f;
        #pragma unroll
        for (int j = 0; j < JD; ++j) {
            const int rowoff = iyl[j] * GXD;
            const float wj = wyl[j];
            #pragma unroll
            for (int k = 0; k < JD; ++k) {
                const float w = wj * wxl[k];
                const float2 v = __half22float2(gh[(size_t)(rowoff + ixl[k]) * BD + b]);
                ar += v.x * w;
                ai += v.y * w;
            }
        }

        const int n = n0 + s;
        const float pr = s_pr[s], pi = s_pi[s];
        out[(size_t)b * NSAMP + n] = make_float2(ar * pr - ai * pi,
                                                 ar * pi + ai * pr);
    }
}

extern "C" void kernel_launch(void* const* d_in, const int* in_sizes, int n_in,
                              void* d_out, int out_size, void* d_ws, size_t ws_size,
                              hipStream_t stream) {
    const float* xr   = (const float*)d_in[0];
    const float* xi   = (const float*)d_in[1];
    const float* sc_y = (const float*)d_in[2];
    const float* sc_x = (const float*)d_in[3];
    const float* wy   = (const float*)d_in[4];
    const float* wx   = (const float*)d_in[5];
    const float* phr  = (const float*)d_in[6];
    const float* phi  = (const float*)d_in[7];
    const int*   iy   = (const int*)d_in[8];
    const int*   ix   = (const int*)d_in[9];

    // Workspace: G1i (8.39 MB fp32 interleaved) | ghat fp16 (8.39 MB interleaved)
    char* ws = (char*)d_ws;
    float4* G1i4 = (float4*)ws;
    float2* gh   = (float2*)(ws + (size_t)HD * GXD * BD * sizeof(float2));
    float2* outp = (float2*)d_out;

    void* args[] = { (void*)&xr, (void*)&xi, (void*)&sc_y, (void*)&sc_x,
                     (void*)&wy, (void*)&wx, (void*)&phr, (void*)&phi,
                     (void*)&iy, (void*)&ix, (void*)&G1i4, (void*)&gh,
                     (void*)&outp };
    hipLaunchCooperativeKernel((const void*)fused_kernel, dim3(NBLK), dim3(256),
                               args, 0, stream);
}

// Round 10
// 125.172 us; speedup vs baseline: 1.9325x; 1.9325x over previous
//
#include <hip/hip_runtime.h>
#include <hip/hip_fp16.h>

#define GYD 512
#define GXD 512
#define HD 256
#define WD 256
#define BD 8
#define NSAMP 100000
#define JD 7
#define NCP 9           // padded LDS stride (8 batch columns + 1)
#define GCH 128         // samples per gather block

// digit-reverse base 8, 3 digits (involution)
__device__ __forceinline__ int dr3(int i) {
    return ((i & 7) << 6) | (i & 56) | ((i >> 6) & 7);
}

// One radix-8 DIT stage over 8 interleaved 512-pt FFTs in LDS.
template<int LEN, int EIGHTH, int TWSH>
__device__ __forceinline__ void r8_stage(float* __restrict__ re, float* __restrict__ im,
                                         const float* __restrict__ twr,
                                         const float* __restrict__ twi, int g) {
    const int c = g & 7;
    const int m = g >> 3;
    const int off = m & (EIGHTH - 1);
    const int blk = m / EIGHTH;
    const int p0 = (blk * LEN + off) * NCP + c;
    float ar[8], ai[8];
    #pragma unroll
    for (int j = 0; j < 8; ++j) {
        ar[j] = re[p0 + j * EIGHTH * NCP];
        ai[j] = im[p0 + j * EIGHTH * NCP];
    }
    if (TWSH >= 0) {
        #pragma unroll
        for (int j = 1; j < 8; ++j) {
            const int idx = (off * j) << (TWSH >= 0 ? TWSH : 0);
            const float cr = twr[idx], ci = twi[idx];
            const float tr = ar[j] * cr - ai[j] * ci;
            ai[j] = ar[j] * ci + ai[j] * cr;
            ar[j] = tr;
        }
    }
    const float e0r = ar[0] + ar[4], e0i = ai[0] + ai[4];
    const float e1r = ar[0] - ar[4], e1i = ai[0] - ai[4];
    const float e2r = ar[2] + ar[6], e2i = ai[2] + ai[6];
    const float e3r = ar[2] - ar[6], e3i = ai[2] - ai[6];
    const float E0r = e0r + e2r, E0i = e0i + e2i;
    const float E2r = e0r - e2r, E2i = e0i - e2i;
    const float E1r = e1r + e3i, E1i = e1i - e3r;   // e1 - i*e3
    const float E3r = e1r - e3i, E3i = e1i + e3r;   // e1 + i*e3

    const float q0r = ar[1] + ar[5], q0i = ai[1] + ai[5];
    const float q1r = ar[1] - ar[5], q1i = ai[1] - ai[5];
    const float q2r = ar[3] + ar[7], q2i = ai[3] + ai[7];
    const float q3r = ar[3] - ar[7], q3i = ai[3] - ai[7];
    const float O0r = q0r + q2r, O0i = q0i + q2i;
    const float O2r = q0r - q2r, O2i = q0i - q2i;
    const float O1r = q1r + q3i, O1i = q1i - q3r;
    const float O3r = q1r - q3i, O3i = q1i + q3r;

    const float S = 0.70710678118654752f;
    const float T0r = O0r,              T0i = O0i;
    const float T1r = S * (O1r + O1i),  T1i = S * (O1i - O1r);
    const float T2r = O2i,              T2i = -O2r;
    const float T3r = S * (O3i - O3r),  T3i = -S * (O3r + O3i);

    re[p0 + 0 * EIGHTH * NCP] = E0r + T0r;  im[p0 + 0 * EIGHTH * NCP] = E0i + T0i;
    re[p0 + 4 * EIGHTH * NCP] = E0r - T0r;  im[p0 + 4 * EIGHTH * NCP] = E0i - T0i;
    re[p0 + 1 * EIGHTH * NCP] = E1r + T1r;  im[p0 + 1 * EIGHTH * NCP] = E1i + T1i;
    re[p0 + 5 * EIGHTH * NCP] = E1r - T1r;  im[p0 + 5 * EIGHTH * NCP] = E1i - T1i;
    re[p0 + 2 * EIGHTH * NCP] = E2r + T2r;  im[p0 + 2 * EIGHTH * NCP] = E2i + T2i;
    re[p0 + 6 * EIGHTH * NCP] = E2r - T2r;  im[p0 + 6 * EIGHTH * NCP] = E2i - T2i;
    re[p0 + 3 * EIGHTH * NCP] = E3r + T3r;  im[p0 + 3 * EIGHTH * NCP] = E3i + T3i;
    re[p0 + 7 * EIGHTH * NCP] = E3r - T3r;  im[p0 + 7 * EIGHTH * NCP] = E3i - T3i;
}

// Kernel A: apodized zero-padded row FFT for ALL 8 batches of one y row.
__global__ __launch_bounds__(512) void rowfft_kernel(
    const float* __restrict__ xr, const float* __restrict__ xi,
    const float* __restrict__ sc_y, const float* __restrict__ sc_x,
    float4* __restrict__ G1i4)
{
    __shared__ float re[512 * NCP];
    __shared__ float im[512 * NCP];
    __shared__ float twr[512];
    __shared__ float twi[512];
    const int t = threadIdx.x;
    const int y = blockIdx.x;

    {   // tw[m] = exp(-2*pi*i*m/512)
        float sn, cs;
        sincospif(-(float)t / 256.0f, &sn, &cs);
        twr[t] = cs; twi[t] = sn;
    }

    const float sy = sc_y[y];
    {
        const int b = t >> 6;               // 0..7
        const int x4 = (t & 63) << 2;       // 0..252 step 4
        const float4 vr = *(const float4*)(xr + b * (HD * WD) + y * WD + x4);
        const float4 vi = *(const float4*)(xi + b * (HD * WD) + y * WD + x4);
        const float4 sx = *(const float4*)(sc_x + x4);
        int p;
        float s;
        s = sy * sx.x; p = dr3(x4 + 0) * NCP + b; re[p] = vr.x * s; im[p] = vi.x * s;
        s = sy * sx.y; p = dr3(x4 + 1) * NCP + b; re[p] = vr.y * s; im[p] = vi.y * s;
        s = sy * sx.z; p = dr3(x4 + 2) * NCP + b; re[p] = vr.z * s; im[p] = vi.z * s;
        s = sy * sx.w; p = dr3(x4 + 3) * NCP + b; re[p] = vr.w * s; im[p] = vi.w * s;
        #pragma unroll
        for (int k = 0; k < 4; ++k) {       // x zero-pad 256..511
            p = dr3(x4 + 256 + k) * NCP + b;
            re[p] = 0.0f; im[p] = 0.0f;
        }
    }
    __syncthreads();
    r8_stage<8, 1, -1>(re, im, twr, twi, t);
    __syncthreads();
    r8_stage<64, 8, 3>(re, im, twr, twi, t);
    __syncthreads();
    r8_stage<512, 64, 0>(re, im, twr, twi, t);
    __syncthreads();

    float4* dst = G1i4 + (size_t)y * 2048;
    #pragma unroll
    for (int iter = 0; iter < 4; ++iter) {
        const int if4 = iter * 512 + t;      // 0..2047
        const int x = if4 >> 2;
        const int b = (if4 & 3) << 1;
        const int p = x * NCP + b;
        dst[if4] = make_float4(re[p], im[p], re[p + 1], im[p + 1]);
    }
}

// Kernel B: zero-padded column FFT for ALL 8 batches of one x column.
// Output ghat in FP16 batch-interleaved: half2(re,im) at [(y*512+x)*8 + b].
__global__ __launch_bounds__(512) void colfft_kernel(
    const float4* __restrict__ G1i4, float2* __restrict__ ghat_f2)
{
    __shared__ float re[512 * NCP];
    __shared__ float im[512 * NCP];
    __shared__ float twr[512];
    __shared__ float twi[512];
    const int t = threadIdx.x;
    const int x = blockIdx.x;

    {
        float sn, cs;
        sincospif(-(float)t / 256.0f, &sn, &cs);
        twr[t] = cs; twi[t] = sn;
    }

    #pragma unroll
    for (int iter = 0; iter < 2; ++iter) {
        const int i = iter * 512 + t;        // 0..1023
        const int yy = i >> 2;               // 0..255
        const int bp = (i & 3) << 1;
        const float4 v = G1i4[((size_t)yy * GXD + x) * 4 + (i & 3)];
        const int p = dr3(yy) * NCP + bp;
        re[p] = v.x; im[p] = v.y; re[p + 1] = v.z; im[p + 1] = v.w;
        const int p2 = dr3(yy + 256) * NCP + bp;   // y zero-pad
        re[p2] = 0.0f; im[p2] = 0.0f; re[p2 + 1] = 0.0f; im[p2 + 1] = 0.0f;
    }
    __syncthreads();
    r8_stage<8, 1, -1>(re, im, twr, twi, t);
    __syncthreads();
    r8_stage<64, 8, 3>(re, im, twr, twi, t);
    __syncthreads();
    r8_stage<512, 64, 0>(re, im, twr, twi, t);
    __syncthreads();

    const float scale = 1.0f / 512.0f;       // ortho: 1/sqrt(512*512)
    #pragma unroll
    for (int iter = 0; iter < 4; ++iter) {
        const int if4 = iter * 512 + t;      // 0..2047
        const int yy = if4 >> 2;             // 0..511
        const int b = (if4 & 3) << 1;        // even batch of the pair
        const int p = yy * NCP + b;
        union { __half2 h[2]; float2 f; } u;
        u.h[0] = __floats2half2_rn(re[p] * scale,     im[p] * scale);
        u.h[1] = __floats2half2_rn(re[p + 1] * scale, im[p + 1] * scale);
        ghat_f2[((size_t)yy * GXD + x) * 4 + (b >> 1)] = u.f;
    }
}

// Kernel C: 7x7 KB gather on fp16 interleaved ghat, quad-vectorized.
// Thread = (sample, batch-quad): one float4 load = 4 batches' (re,im) per tap.
// 4x fewer load instructions than the half2-per-lane mapping; 16 B/lane.
__global__ __launch_bounds__(256) void gather_kernel(
    const float4* __restrict__ gh4,          // ghat as float4: 2 per grid point
    const float* __restrict__ wy, const float* __restrict__ wx,
    const float* __restrict__ phr, const float* __restrict__ phi,
    const int* __restrict__ iy, const int* __restrict__ ix,
    float2* __restrict__ out)
{
    __shared__ int   s_iy[GCH * JD];
    __shared__ int   s_ix[GCH * JD];
    __shared__ float s_wy[GCH * JD];
    __shared__ float s_wx[GCH * JD];
    __shared__ float s_pr[GCH];
    __shared__ float s_pi[GCH];
    const int t = threadIdx.x;
    const int n0 = blockIdx.x * GCH;

    for (int i = t; i < GCH * JD; i += 256) {
        const int g = n0 * JD + i;
        if (g < NSAMP * JD) {
            s_iy[i] = iy[g];
            s_ix[i] = ix[g];
            s_wy[i] = wy[g];
            s_wx[i] = wx[g];
        } else {
            s_iy[i] = 0; s_ix[i] = 0; s_wy[i] = 0.0f; s_wx[i] = 0.0f;
        }
    }
    if (t < GCH) {
        const int n = n0 + t;
        s_pr[t] = (n < NSAMP) ? phr[n] : 0.0f;
        s_pi[t] = (n < NSAMP) ? phi[n] : 0.0f;
    }
    __syncthreads();

    const int q = t & 1;                     // batch quad: batches 4q..4q+3
    const int s = t >> 1;                    // local sample 0..127
    const int n = n0 + s;
    const int base = s * JD;

    int iyl[JD], ixl[JD];
    float wyl[JD], wxl[JD];
    #pragma unroll
    for (int j = 0; j < JD; ++j) {
        iyl[j] = s_iy[base + j];
        ixl[j] = s_ix[base + j];
        wyl[j] = s_wy[base + j];
        wxl[j] = s_wx[base + j];
    }

    float ar[4] = {0, 0, 0, 0}, ai[4] = {0, 0, 0, 0};
    #pragma unroll
    for (int j = 0; j < JD; ++j) {
        const int rowoff = iyl[j] * GXD;
        const float wj = wyl[j];
        #pragma unroll
        for (int k = 0; k < JD; ++k) {
            const float w = wj * wxl[k];
            const float4 v = gh4[(size_t)(rowoff + ixl[k]) * 2 + q];
            const __half2* hp = (const __half2*)&v;
            #pragma unroll
            for (int i = 0; i < 4; ++i) {
                const float2 f = __half22float2(hp[i]);
                ar[i] += f.x * w;
                ai[i] += f.y * w;
            }
        }
    }

    if (n < NSAMP) {
        const float pr = s_pr[s], pi = s_pi[s];
        #pragma unroll
        for (int i = 0; i < 4; ++i) {
            out[(size_t)(q * 4 + i) * NSAMP + n] =
                make_float2(ar[i] * pr - ai[i] * pi, ar[i] * pi + ai[i] * pr);
        }
    }
}

extern "C" void kernel_launch(void* const* d_in, const int* in_sizes, int n_in,
                              void* d_out, int out_size, void* d_ws, size_t ws_size,
                              hipStream_t stream) {
    const float* xr   = (const float*)d_in[0];
    const float* xi   = (const float*)d_in[1];
    const float* sc_y = (const float*)d_in[2];
    const float* sc_x = (const float*)d_in[3];
    const float* wy   = (const float*)d_in[4];
    const float* wx   = (const float*)d_in[5];
    const float* phr  = (const float*)d_in[6];
    const float* phi  = (const float*)d_in[7];
    const int*   iy   = (const int*)d_in[8];
    const int*   ix   = (const int*)d_in[9];

    // Workspace: G1i (8.39 MB fp32 interleaved) | ghat fp16 (8.39 MB interleaved)
    char* ws = (char*)d_ws;
    float4* G1i4 = (float4*)ws;
    float2* gh   = (float2*)(ws + (size_t)HD * GXD * BD * sizeof(float2));

    rowfft_kernel<<<HD, 512, 0, stream>>>(xr, xi, sc_y, sc_x, G1i4);
    colfft_kernel<<<GXD, 512, 0, stream>>>(G1i4, gh);
    gather_kernel<<<(NSAMP + GCH - 1) / GCH, 256, 0, stream>>>(
        (const float4*)gh, wy, wx, phr, phi, iy, ix, (float2*)d_out);
}

// Round 11
// 117.648 us; speedup vs baseline: 2.0560x; 1.0639x over previous
//
#include <hip/hip_runtime.h>
#include <hip/hip_fp16.h>

#define GYD 512
#define GXD 512
#define HD 256
#define WD 256
#define BD 8
#define NSAMP 100000
#define JD 7
#define NCP 9           // padded LDS stride (8 batch columns + 1)

// digit-reverse base 8, 3 digits (involution)
__device__ __forceinline__ int dr3(int i) {
    return ((i & 7) << 6) | (i & 56) | ((i >> 6) & 7);
}

// One radix-8 DIT stage over 8 interleaved 512-pt FFTs in LDS.
template<int LEN, int EIGHTH, int TWSH>
__device__ __forceinline__ void r8_stage(float* __restrict__ re, float* __restrict__ im,
                                         const float* __restrict__ twr,
                                         const float* __restrict__ twi, int g) {
    const int c = g & 7;
    const int m = g >> 3;
    const int off = m & (EIGHTH - 1);
    const int blk = m / EIGHTH;
    const int p0 = (blk * LEN + off) * NCP + c;
    float ar[8], ai[8];
    #pragma unroll
    for (int j = 0; j < 8; ++j) {
        ar[j] = re[p0 + j * EIGHTH * NCP];
        ai[j] = im[p0 + j * EIGHTH * NCP];
    }
    if (TWSH >= 0) {
        #pragma unroll
        for (int j = 1; j < 8; ++j) {
            const int idx = (off * j) << (TWSH >= 0 ? TWSH : 0);
            const float cr = twr[idx], ci = twi[idx];
            const float tr = ar[j] * cr - ai[j] * ci;
            ai[j] = ar[j] * ci + ai[j] * cr;
            ar[j] = tr;
        }
    }
    const float e0r = ar[0] + ar[4], e0i = ai[0] + ai[4];
    const float e1r = ar[0] - ar[4], e1i = ai[0] - ai[4];
    const float e2r = ar[2] + ar[6], e2i = ai[2] + ai[6];
    const float e3r = ar[2] - ar[6], e3i = ai[2] - ai[6];
    const float E0r = e0r + e2r, E0i = e0i + e2i;
    const float E2r = e0r - e2r, E2i = e0i - e2i;
    const float E1r = e1r + e3i, E1i = e1i - e3r;   // e1 - i*e3
    const float E3r = e1r - e3i, E3i = e1i + e3r;   // e1 + i*e3

    const float q0r = ar[1] + ar[5], q0i = ai[1] + ai[5];
    const float q1r = ar[1] - ar[5], q1i = ai[1] - ai[5];
    const float q2r = ar[3] + ar[7], q2i = ai[3] + ai[7];
    const float q3r = ar[3] - ar[7], q3i = ai[3] - ai[7];
    const float O0r = q0r + q2r, O0i = q0i + q2i;
    const float O2r = q0r - q2r, O2i = q0i - q2i;
    const float O1r = q1r + q3i, O1i = q1i - q3r;
    const float O3r = q1r - q3i, O3i = q1i + q3r;

    const float S = 0.70710678118654752f;
    const float T0r = O0r,              T0i = O0i;
    const float T1r = S * (O1r + O1i),  T1i = S * (O1i - O1r);
    const float T2r = O2i,              T2i = -O2r;
    const float T3r = S * (O3i - O3r),  T3i = -S * (O3r + O3i);

    re[p0 + 0 * EIGHTH * NCP] = E0r + T0r;  im[p0 + 0 * EIGHTH * NCP] = E0i + T0i;
    re[p0 + 4 * EIGHTH * NCP] = E0r - T0r;  im[p0 + 4 * EIGHTH * NCP] = E0i - T0i;
    re[p0 + 1 * EIGHTH * NCP] = E1r + T1r;  im[p0 + 1 * EIGHTH * NCP] = E1i + T1i;
    re[p0 + 5 * EIGHTH * NCP] = E1r - T1r;  im[p0 + 5 * EIGHTH * NCP] = E1i - T1i;
    re[p0 + 2 * EIGHTH * NCP] = E2r + T2r;  im[p0 + 2 * EIGHTH * NCP] = E2i + T2i;
    re[p0 + 6 * EIGHTH * NCP] = E2r - T2r;  im[p0 + 6 * EIGHTH * NCP] = E2i - T2i;
    re[p0 + 3 * EIGHTH * NCP] = E3r + T3r;  im[p0 + 3 * EIGHTH * NCP] = E3i + T3i;
    re[p0 + 7 * EIGHTH * NCP] = E3r - T3r;  im[p0 + 7 * EIGHTH * NCP] = E3i - T3i;
}

// Kernel A: apodized zero-padded row FFT for ALL 8 batches of one y row.
__global__ __launch_bounds__(512) void rowfft_kernel(
    const float* __restrict__ xr, const float* __restrict__ xi,
    const float* __restrict__ sc_y, const float* __restrict__ sc_x,
    float4* __restrict__ G1i4)
{
    __shared__ float re[512 * NCP];
    __shared__ float im[512 * NCP];
    __shared__ float twr[512];
    __shared__ float twi[512];
    const int t = threadIdx.x;
    const int y = blockIdx.x;

    {   // tw[m] = exp(-2*pi*i*m/512)
        float sn, cs;
        sincospif(-(float)t / 256.0f, &sn, &cs);
        twr[t] = cs; twi[t] = sn;
    }

    const float sy = sc_y[y];
    {
        const int b = t >> 6;               // 0..7
        const int x4 = (t & 63) << 2;       // 0..252 step 4
        const float4 vr = *(const float4*)(xr + b * (HD * WD) + y * WD + x4);
        const float4 vi = *(const float4*)(xi + b * (HD * WD) + y * WD + x4);
        const float4 sx = *(const float4*)(sc_x + x4);
        int p;
        float s;
        s = sy * sx.x; p = dr3(x4 + 0) * NCP + b; re[p] = vr.x * s; im[p] = vi.x * s;
        s = sy * sx.y; p = dr3(x4 + 1) * NCP + b; re[p] = vr.y * s; im[p] = vi.y * s;
        s = sy * sx.z; p = dr3(x4 + 2) * NCP + b; re[p] = vr.z * s; im[p] = vi.z * s;
        s = sy * sx.w; p = dr3(x4 + 3) * NCP + b; re[p] = vr.w * s; im[p] = vi.w * s;
        #pragma unroll
        for (int k = 0; k < 4; ++k) {       // x zero-pad 256..511
            p = dr3(x4 + 256 + k) * NCP + b;
            re[p] = 0.0f; im[p] = 0.0f;
        }
    }
    __syncthreads();
    r8_stage<8, 1, -1>(re, im, twr, twi, t);
    __syncthreads();
    r8_stage<64, 8, 3>(re, im, twr, twi, t);
    __syncthreads();
    r8_stage<512, 64, 0>(re, im, twr, twi, t);
    __syncthreads();

    float4* dst = G1i4 + (size_t)y * 2048;
    #pragma unroll
    for (int iter = 0; iter < 4; ++iter) {
        const int if4 = iter * 512 + t;      // 0..2047
        const int x = if4 >> 2;
        const int b = (if4 & 3) << 1;
        const int p = x * NCP + b;
        dst[if4] = make_float4(re[p], im[p], re[p + 1], im[p + 1]);
    }
}

// Kernel B: zero-padded column FFT for ALL 8 batches of one x column.
// Output ghat in FP16 batch-interleaved: half2(re,im) at [(y*512+x)*8 + b].
__global__ __launch_bounds__(512) void colfft_kernel(
    const float4* __restrict__ G1i4, float2* __restrict__ ghat_f2)
{
    __shared__ float re[512 * NCP];
    __shared__ float im[512 * NCP];
    __shared__ float twr[512];
    __shared__ float twi[512];
    const int t = threadIdx.x;
    const int x = blockIdx.x;

    {
        float sn, cs;
        sincospif(-(float)t / 256.0f, &sn, &cs);
        twr[t] = cs; twi[t] = sn;
    }

    #pragma unroll
    for (int iter = 0; iter < 2; ++iter) {
        const int i = iter * 512 + t;        // 0..1023
        const int yy = i >> 2;               // 0..255
        const int bp = (i & 3) << 1;
        const float4 v = G1i4[((size_t)yy * GXD + x) * 4 + (i & 3)];
        const int p = dr3(yy) * NCP + bp;
        re[p] = v.x; im[p] = v.y; re[p + 1] = v.z; im[p + 1] = v.w;
        const int p2 = dr3(yy + 256) * NCP + bp;   // y zero-pad
        re[p2] = 0.0f; im[p2] = 0.0f; re[p2 + 1] = 0.0f; im[p2 + 1] = 0.0f;
    }
    __syncthreads();
    r8_stage<8, 1, -1>(re, im, twr, twi, t);
    __syncthreads();
    r8_stage<64, 8, 3>(re, im, twr, twi, t);
    __syncthreads();
    r8_stage<512, 64, 0>(re, im, twr, twi, t);
    __syncthreads();

    const float scale = 1.0f / 512.0f;       // ortho: 1/sqrt(512*512)
    #pragma unroll
    for (int iter = 0; iter < 4; ++iter) {
        const int if4 = iter * 512 + t;      // 0..2047
        const int yy = if4 >> 2;             // 0..511
        const int b = (if4 & 3) << 1;        // even batch of the pair
        const int p = yy * NCP + b;
        union { __half2 h[2]; float2 f; } u;
        u.h[0] = __floats2half2_rn(re[p] * scale,     im[p] * scale);
        u.h[1] = __floats2half2_rn(re[p + 1] * scale, im[p + 1] * scale);
        ghat_f2[((size_t)yy * GXD + x) * 4 + (b >> 1)] = u.f;
    }
}

// Kernel C: 7x7 KB gather, segment-vectorized at full TLP.
// 8 lanes/sample (sub = t&7): q = sub&1 (batch quad), xo = sub>>1 (x offset).
// Per j-row each lane does TWO float4 loads covering grid points ix0+xo and
// ix0+xo+4 (8 points cover the 7 taps; o=7 weight-masked to 0). Per-lane VMEM
// 49 -> 14 at UNCHANGED thread count (R9/R10 showed TLP is the binding
// resource). Final 4-lane x-reduction via __shfl_xor(2,4).
__global__ __launch_bounds__(256) void gather_kernel(
    const float4* __restrict__ gh4,          // 2 float4 per grid point
    const float* __restrict__ wy, const float* __restrict__ wx,
    const float* __restrict__ phr, const float* __restrict__ phi,
    const int* __restrict__ iy, const int* __restrict__ ix,
    float2* __restrict__ out)
{
    __shared__ int   s_iy[32 * JD];
    __shared__ float s_wy[32 * JD];
    __shared__ float s_wx[32 * JD];
    __shared__ int   s_ix0[32];
    __shared__ float s_pr[32];
    __shared__ float s_pi[32];
    const int t = threadIdx.x;
    const int n0 = blockIdx.x * 32;          // 3125 * 32 = 100000 exact

    if (t < 224) {                           // 32 samples x 7 taps, coalesced
        const int g = n0 * JD + t;
        s_iy[t] = iy[g];
        s_wy[t] = wy[g];
        s_wx[t] = wx[g];
    } else {                                 // threads 224..255: phase + ix0
        const int s2 = t - 224;
        s_pr[s2] = phr[n0 + s2];
        s_pi[s2] = phi[n0 + s2];
        s_ix0[s2] = ix[(n0 + s2) * JD];      // first x tap
    }
    __syncthreads();

    const int sub = t & 7;
    const int q   = sub & 1;                 // batch quad 0/1
    const int xo  = sub >> 1;                // x offset 0..3
    const int s   = t >> 3;                  // local sample 0..31
    const int n   = n0 + s;
    const int base = s * JD;

    const int ix0 = s_ix0[s];
    const float wxa = s_wx[base + xo];                         // o = xo
    const float wxb = (xo < 3) ? s_wx[base + xo + 4] : 0.0f;   // o = xo+4 (7 -> 0)
    const int xA = (ix0 + xo) & (GXD - 1);
    const int xB = (ix0 + xo + 4) & (GXD - 1);

    int   iyl[JD];
    float wyl[JD];
    #pragma unroll
    for (int j = 0; j < JD; ++j) {
        iyl[j] = s_iy[base + j];
        wyl[j] = s_wy[base + j];
    }

    float ar[4] = {0, 0, 0, 0}, ai[4] = {0, 0, 0, 0};
    #pragma unroll
    for (int j = 0; j < JD; ++j) {
        const int rowoff = iyl[j] * GXD;
        const float wA = wyl[j] * wxa;
        const float wB = wyl[j] * wxb;
        const float4 vA = gh4[(size_t)(rowoff + xA) * 2 + q];
        const float4 vB = gh4[(size_t)(rowoff + xB) * 2 + q];
        const __half2* hA = (const __half2*)&vA;
        const __half2* hB = (const __half2*)&vB;
        #pragma unroll
        for (int i = 0; i < 4; ++i) {
            const float2 fA = __half22float2(hA[i]);
            const float2 fB = __half22float2(hB[i]);
            ar[i] += fA.x * wA + fB.x * wB;
            ai[i] += fA.y * wA + fB.y * wB;
        }
    }

    // Fold the 4 x-lanes of each quad (XOR over sub-lane bits 1,2).
    #pragma unroll
    for (int i = 0; i < 4; ++i) {
        ar[i] += __shfl_xor(ar[i], 2);
        ai[i] += __shfl_xor(ai[i], 2);
        ar[i] += __shfl_xor(ar[i], 4);
        ai[i] += __shfl_xor(ai[i], 4);
    }

    if (xo == 0) {
        const float pr = s_pr[s], pi = s_pi[s];
        #pragma unroll
        for (int i = 0; i < 4; ++i) {
            out[(size_t)(q * 4 + i) * NSAMP + n] =
                make_float2(ar[i] * pr - ai[i] * pi, ar[i] * pi + ai[i] * pr);
        }
    }
}

extern "C" void kernel_launch(void* const* d_in, const int* in_sizes, int n_in,
                              void* d_out, int out_size, void* d_ws, size_t ws_size,
                              hipStream_t stream) {
    const float* xr   = (const float*)d_in[0];
    const float* xi   = (const float*)d_in[1];
    const float* sc_y = (const float*)d_in[2];
    const float* sc_x = (const float*)d_in[3];
    const float* wy   = (const float*)d_in[4];
    const float* wx   = (const float*)d_in[5];
    const float* phr  = (const float*)d_in[6];
    const float* phi  = (const float*)d_in[7];
    const int*   iy   = (const int*)d_in[8];
    const int*   ix   = (const int*)d_in[9];

    // Workspace: G1i (8.39 MB fp32 interleaved) | ghat fp16 (8.39 MB interleaved)
    char* ws = (char*)d_ws;
    float4* G1i4 = (float4*)ws;
    float2* gh   = (float2*)(ws + (size_t)HD * GXD * BD * sizeof(float2));

    rowfft_kernel<<<HD, 512, 0, stream>>>(xr, xi, sc_y, sc_x, G1i4);
    colfft_kernel<<<GXD, 512, 0, stream>>>(G1i4, gh);
    gather_kernel<<<NSAMP / 32, 256, 0, stream>>>(
        (const float4*)gh, wy, wx, phr, phi, iy, ix, (float2*)d_out);
}

// Round 12
// 113.725 us; speedup vs baseline: 2.1270x; 1.0345x over previous
//
#include <hip/hip_runtime.h>
#include <hip/hip_fp16.h>

#define GYD 512
#define GXD 512
#define HD 256
#define WD 256
#define BD 8
#define NSAMP 100000
#define JD 7
#define NCP 9           // padded LDS stride (8 batch columns + 1)

// digit-reverse base 8, 3 digits (involution)
__device__ __forceinline__ int dr3(int i) {
    return ((i & 7) << 6) | (i & 56) | ((i >> 6) & 7);
}

// One radix-8 DIT stage over 8 interleaved 512-pt FFTs in LDS.
// ZHI: inputs j=4..7 are structurally zero (zero-padded upper half, only
// stage 1 sees them) -> read 4 points, specialized half-DFT.
template<int LEN, int EIGHTH, int TWSH, bool ZHI>
__device__ __forceinline__ void r8_stage(float* __restrict__ re, float* __restrict__ im,
                                         const float* __restrict__ twr,
                                         const float* __restrict__ twi, int g) {
    const int c = g & 7;
    const int m = g >> 3;
    const int off = m & (EIGHTH - 1);
    const int blk = m / EIGHTH;
    const int p0 = (blk * LEN + off) * NCP + c;

    float E0r, E0i, E1r, E1i, E2r, E2i, E3r, E3i;
    float O0r, O0i, O1r, O1i, O2r, O2i, O3r, O3i;

    if (ZHI) {
        // a4..a7 == 0: evens reduce to {a0,a2}, odds to {a1,a3}.
        const float a0r = re[p0 + 0 * EIGHTH * NCP], a0i = im[p0 + 0 * EIGHTH * NCP];
        const float a1r = re[p0 + 1 * EIGHTH * NCP], a1i = im[p0 + 1 * EIGHTH * NCP];
        const float a2r = re[p0 + 2 * EIGHTH * NCP], a2i = im[p0 + 2 * EIGHTH * NCP];
        const float a3r = re[p0 + 3 * EIGHTH * NCP], a3i = im[p0 + 3 * EIGHTH * NCP];
        E0r = a0r + a2r; E0i = a0i + a2i;
        E2r = a0r - a2r; E2i = a0i - a2i;
        E1r = a0r + a2i; E1i = a0i - a2r;     // a0 - i*a2
        E3r = a0r - a2i; E3i = a0i + a2r;     // a0 + i*a2
        O0r = a1r + a3r; O0i = a1i + a3i;
        O2r = a1r - a3r; O2i = a1i - a3i;
        O1r = a1r + a3i; O1i = a1i - a3r;     // a1 - i*a3
        O3r = a1r - a3i; O3i = a1i + a3r;     // a1 + i*a3
    } else {
        float ar[8], ai[8];
        #pragma unroll
        for (int j = 0; j < 8; ++j) {
            ar[j] = re[p0 + j * EIGHTH * NCP];
            ai[j] = im[p0 + j * EIGHTH * NCP];
        }
        if (TWSH >= 0) {
            #pragma unroll
            for (int j = 1; j < 8; ++j) {
                const int idx = (off * j) << (TWSH >= 0 ? TWSH : 0);
                const float cr = twr[idx], ci = twi[idx];
                const float tr = ar[j] * cr - ai[j] * ci;
                ai[j] = ar[j] * ci + ai[j] * cr;
                ar[j] = tr;
            }
        }
        const float e0r = ar[0] + ar[4], e0i = ai[0] + ai[4];
        const float e1r = ar[0] - ar[4], e1i = ai[0] - ai[4];
        const float e2r = ar[2] + ar[6], e2i = ai[2] + ai[6];
        const float e3r = ar[2] - ar[6], e3i = ai[2] - ai[6];
        E0r = e0r + e2r; E0i = e0i + e2i;
        E2r = e0r - e2r; E2i = e0i - e2i;
        E1r = e1r + e3i; E1i = e1i - e3r;     // e1 - i*e3
        E3r = e1r - e3i; E3i = e1i + e3r;     // e1 + i*e3

        const float q0r = ar[1] + ar[5], q0i = ai[1] + ai[5];
        const float q1r = ar[1] - ar[5], q1i = ai[1] - ai[5];
        const float q2r = ar[3] + ar[7], q2i = ai[3] + ai[7];
        const float q3r = ar[3] - ar[7], q3i = ai[3] - ai[7];
        O0r = q0r + q2r; O0i = q0i + q2i;
        O2r = q0r - q2r; O2i = q0i - q2i;
        O1r = q1r + q3i; O1i = q1i - q3r;
        O3r = q1r - q3i; O3i = q1i + q3r;
    }

    const float S = 0.70710678118654752f;
    const float T0r = O0r,              T0i = O0i;
    const float T1r = S * (O1r + O1i),  T1i = S * (O1i - O1r);
    const float T2r = O2i,              T2i = -O2r;
    const float T3r = S * (O3i - O3r),  T3i = -S * (O3r + O3i);

    re[p0 + 0 * EIGHTH * NCP] = E0r + T0r;  im[p0 + 0 * EIGHTH * NCP] = E0i + T0i;
    re[p0 + 4 * EIGHTH * NCP] = E0r - T0r;  im[p0 + 4 * EIGHTH * NCP] = E0i - T0i;
    re[p0 + 1 * EIGHTH * NCP] = E1r + T1r;  im[p0 + 1 * EIGHTH * NCP] = E1i + T1i;
    re[p0 + 5 * EIGHTH * NCP] = E1r - T1r;  im[p0 + 5 * EIGHTH * NCP] = E1i - T1i;
    re[p0 + 2 * EIGHTH * NCP] = E2r + T2r;  im[p0 + 2 * EIGHTH * NCP] = E2i + T2i;
    re[p0 + 6 * EIGHTH * NCP] = E2r - T2r;  im[p0 + 6 * EIGHTH * NCP] = E2i - T2i;
    re[p0 + 3 * EIGHTH * NCP] = E3r + T3r;  im[p0 + 3 * EIGHTH * NCP] = E3i + T3i;
    re[p0 + 7 * EIGHTH * NCP] = E3r - T3r;  im[p0 + 7 * EIGHTH * NCP] = E3i - T3i;
}

// Kernel A: apodized zero-padded row FFT for ALL 8 batches of one y row.
// fp16 output G1h[(y*512+x)*8 + b] = half2(re,im) -- halves write traffic.
__global__ __launch_bounds__(512) void rowfft_kernel(
    const float* __restrict__ xr, const float* __restrict__ xi,
    const float* __restrict__ sc_y, const float* __restrict__ sc_x,
    float4* __restrict__ G1h4)
{
    __shared__ float re[512 * NCP];
    __shared__ float im[512 * NCP];
    __shared__ float twr[512];
    __shared__ float twi[512];
    const int t = threadIdx.x;
    const int y = blockIdx.x;

    {   // tw[m] = exp(-2*pi*i*m/512)
        float sn, cs;
        sincospif(-(float)t / 256.0f, &sn, &cs);
        twr[t] = cs; twi[t] = sn;
    }

    const float sy = sc_y[y];
    {
        const int b = t >> 6;               // 0..7
        const int x4 = (t & 63) << 2;       // 0..252 step 4
        const float4 vr = *(const float4*)(xr + b * (HD * WD) + y * WD + x4);
        const float4 vi = *(const float4*)(xi + b * (HD * WD) + y * WD + x4);
        const float4 sx = *(const float4*)(sc_x + x4);
        int p;
        float s;
        s = sy * sx.x; p = dr3(x4 + 0) * NCP + b; re[p] = vr.x * s; im[p] = vi.x * s;
        s = sy * sx.y; p = dr3(x4 + 1) * NCP + b; re[p] = vr.y * s; im[p] = vi.y * s;
        s = sy * sx.z; p = dr3(x4 + 2) * NCP + b; re[p] = vr.z * s; im[p] = vi.z * s;
        s = sy * sx.w; p = dr3(x4 + 3) * NCP + b; re[p] = vr.w * s; im[p] = vi.w * s;
        // upper half (x 256..511) is structurally zero: never written, never read
        // (lands at positions p&7 >= 4, consumed only by the ZHI stage 1).
    }
    __syncthreads();
    r8_stage<8, 1, -1, true>(re, im, twr, twi, t);
    __syncthreads();
    r8_stage<64, 8, 3, false>(re, im, twr, twi, t);
    __syncthreads();
    r8_stage<512, 64, 0, false>(re, im, twr, twi, t);
    __syncthreads();

    // fp16 pack: row = 1024 float4; float4 f covers x = f>>1, batches (f&1)*4..+3.
    float4* dst = G1h4 + (size_t)y * 1024;
    #pragma unroll
    for (int iter = 0; iter < 2; ++iter) {
        const int f = iter * 512 + t;        // 0..1023
        const int x = f >> 1;
        const int b0 = (f & 1) * 4;
        const int p = x * NCP + b0;
        union { __half2 h[4]; float4 f4; } u;
        #pragma unroll
        for (int i = 0; i < 4; ++i)
            u.h[i] = __floats2half2_rn(re[p + i], im[p + i]);
        dst[f] = u.f4;
    }
}

// Kernel B: zero-padded column FFT for ALL 8 batches of one x column.
// fp16 input G1h; fp16 output ghat (batch-interleaved half2).
__global__ __launch_bounds__(512) void colfft_kernel(
    const float4* __restrict__ G1h4, float2* __restrict__ ghat_f2)
{
    __shared__ float re[512 * NCP];
    __shared__ float im[512 * NCP];
    __shared__ float twr[512];
    __shared__ float twi[512];
    const int t = threadIdx.x;
    const int x = blockIdx.x;

    {
        float sn, cs;
        sincospif(-(float)t / 256.0f, &sn, &cs);
        twr[t] = cs; twi[t] = sn;
    }

    {   // one float4 per thread: yy = t>>1 (0..255), slot = t&1 (batch half)
        const int yy = t >> 1;
        const int slot = t & 1;
        union { __half2 h[4]; float4 f4; } u;
        u.f4 = G1h4[(size_t)yy * 1024 + x * 2 + slot];
        const int p = dr3(yy) * NCP + slot * 4;
        #pragma unroll
        for (int i = 0; i < 4; ++i) {
            const float2 v = __half22float2(u.h[i]);
            re[p + i] = v.x;
            im[p + i] = v.y;
        }
        // y 256..511 structurally zero (positions p&7 >= 4): never written.
    }
    __syncthreads();
    r8_stage<8, 1, -1, true>(re, im, twr, twi, t);
    __syncthreads();
    r8_stage<64, 8, 3, false>(re, im, twr, twi, t);
    __syncthreads();
    r8_stage<512, 64, 0, false>(re, im, twr, twi, t);
    __syncthreads();

    const float scale = 1.0f / 512.0f;       // ortho: 1/sqrt(512*512)
    #pragma unroll
    for (int iter = 0; iter < 4; ++iter) {
        const int if4 = iter * 512 + t;      // 0..2047
        const int yy = if4 >> 2;             // 0..511
        const int b = (if4 & 3) << 1;        // even batch of the pair
        const int p = yy * NCP + b;
        union { __half2 h[2]; float2 f; } u;
        u.h[0] = __floats2half2_rn(re[p] * scale,     im[p] * scale);
        u.h[1] = __floats2half2_rn(re[p + 1] * scale, im[p + 1] * scale);
        ghat_f2[((size_t)yy * GXD + x) * 4 + (b >> 1)] = u.f;
    }
}

// Kernel C: 7x7 KB gather on fp16 interleaved ghat (R8 mapping -- measured best:
// 8 lanes/sample (lane=batch), half2 per tap, full 800k-thread TLP).
__global__ __launch_bounds__(256) void gather_kernel(
    const __half2* __restrict__ gh,
    const float* __restrict__ wy, const float* __restrict__ wx,
    const float* __restrict__ phr, const float* __restrict__ phi,
    const int* __restrict__ iy, const int* __restrict__ ix,
    float2* __restrict__ out)
{
    __shared__ int   s_iy[32 * JD];
    __shared__ int   s_ix[32 * JD];
    __shared__ float s_wy[32 * JD];
    __shared__ float s_wx[32 * JD];
    __shared__ float s_pr[32];
    __shared__ float s_pi[32];
    const int t = threadIdx.x;
    const int n0 = blockIdx.x * 32;          // 3125 * 32 = 100000 exact

    if (t < 224) {                           // 32 samples x 7 taps, coalesced
        const int g = n0 * JD + t;
        s_iy[t] = iy[g];
        s_ix[t] = ix[g];
        s_wy[t] = wy[g];
        s_wx[t] = wx[g];
    } else {                                 // threads 224..255: phase
        const int s = t - 224;
        s_pr[s] = phr[n0 + s];
        s_pi[s] = phi[n0 + s];
    }
    __syncthreads();

    const int b = t & 7;
    const int s = t >> 3;                    // local sample 0..31
    const int base = s * JD;

    int iyl[JD], ixl[JD];
    float wyl[JD], wxl[JD];
    #pragma unroll
    for (int j = 0; j < JD; ++j) {
        iyl[j] = s_iy[base + j];
        ixl[j] = s_ix[base + j];
        wyl[j] = s_wy[base + j];
        wxl[j] = s_wx[base + j];
    }

    float ar = 0.0f, ai = 0.0f;
    #pragma unroll
    for (int j = 0; j < JD; ++j) {
        const int rowoff = iyl[j] * GXD;
        const float wj = wyl[j];
        #pragma unroll
        for (int k = 0; k < JD; ++k) {
            const float w = wj * wxl[k];
            const float2 v = __half22float2(gh[(size_t)(rowoff + ixl[k]) * BD + b]);
            ar += v.x * w;
            ai += v.y * w;
        }
    }

    const int n = n0 + s;
    const float pr = s_pr[s], pi = s_pi[s];
    out[(size_t)b * NSAMP + n] = make_float2(ar * pr - ai * pi,
                                             ar * pi + ai * pr);
}

extern "C" void kernel_launch(void* const* d_in, const int* in_sizes, int n_in,
                              void* d_out, int out_size, void* d_ws, size_t ws_size,
                              hipStream_t stream) {
    const float* xr   = (const float*)d_in[0];
    const float* xi   = (const float*)d_in[1];
    const float* sc_y = (const float*)d_in[2];
    const float* sc_x = (const float*)d_in[3];
    const float* wy   = (const float*)d_in[4];
    const float* wx   = (const float*)d_in[5];
    const float* phr  = (const float*)d_in[6];
    const float* phi  = (const float*)d_in[7];
    const int*   iy   = (const int*)d_in[8];
    const int*   ix   = (const int*)d_in[9];

    // Workspace: G1h fp16 (4.19 MB) | ghat fp16 (8.39 MB)
    char* ws = (char*)d_ws;
    float4* G1h4 = (float4*)ws;
    float2* gh   = (float2*)(ws + (size_t)HD * GXD * BD * sizeof(__half2));

    rowfft_kernel<<<HD, 512, 0, stream>>>(xr, xi, sc_y, sc_x, G1h4);
    colfft_kernel<<<GXD, 512, 0, stream>>>(G1h4, gh);
    gather_kernel<<<NSAMP / 32, 256, 0, stream>>>(
        (const __half2*)gh, wy, wx, phr, phi, iy, ix, (float2*)d_out);
}